// Round 8
// baseline (1407.249 us; speedup 1.0000x reference)
//
#include <hip/hip_runtime.h>
#include <hip/hip_fp16.h>
#include <hip/hip_cooperative_groups.h>
#include <stdint.h>

namespace cg = cooperative_groups;

#define NROWS 8192
#define DIM 64
#define EPS 0.1f

typedef float f32x4 __attribute__((ext_vector_type(4)));
typedef short s16x8 __attribute__((ext_vector_type(8)));
typedef _Float16 h2 __attribute__((ext_vector_type(2)));

// ---------- helpers ----------

__device__ __forceinline__ float wave_reduce_add(float v) {
  #pragma unroll
  for (int off = 32; off > 0; off >>= 1) v += __shfl_down(v, off, 64);
  return v;
}

__device__ __forceinline__ unsigned short f2bf(float f) {
  uint32_t u = __float_as_uint(f);
  return (unsigned short)((u + 0x7fffu + ((u >> 16) & 1u)) >> 16);
}

// Packed f16 pair from two e5m2 bytes of wd (byte<<8 == exact f16).
#define SEL01 0x01040004u
#define SEL23 0x03040204u
__device__ __forceinline__ h2 kpair(uint32_t wd, uint32_t sel) {
  return __builtin_bit_cast(h2, __builtin_amdgcn_perm(0u, wd, sel));
}

#define MV_DOT(d, xlo, xhi, accA, accB)                                              \
  accA = __builtin_amdgcn_fdot2(kpair((d), SEL01), __builtin_bit_cast(h2, (xlo)),    \
                                accA, false);                                        \
  accB = __builtin_amdgcn_fdot2(kpair((d), SEL23), __builtin_bit_cast(h2, (xhi)),    \
                                accB, false);

#define FN_DOT(d, xlo, xhi, s1, s2)                                                  \
  {                                                                                  \
    h2 k01 = kpair((d), SEL01), k23 = kpair((d), SEL23);                             \
    h2 x01 = __builtin_bit_cast(h2, (xlo)), x23 = __builtin_bit_cast(h2, (xhi));     \
    s1 = __builtin_amdgcn_fdot2(k01, x01, s1, false);                                \
    s1 = __builtin_amdgcn_fdot2(k23, x23, s1, false);                                \
    float kk;                                                                        \
    kk = (float)k01.x; s2 = fmaf(kk * (float)x01.x, __logf(fmaxf(kk, 1e-7f)), s2);   \
    kk = (float)k01.y; s2 = fmaf(kk * (float)x01.y, __logf(fmaxf(kk, 1e-7f)), s2);   \
    kk = (float)k23.x; s2 = fmaf(kk * (float)x23.x, __logf(fmaxf(kk, 1e-7f)), s2);   \
    kk = (float)k23.y; s2 = fmaf(kk * (float)x23.y, __logf(fmaxf(kk, 1e-7f)), s2);   \
  }

// ---------- small kernels ----------

__global__ __launch_bounds__(256) void rownorm_kernel(
    const float* __restrict__ P, const float* __restrict__ Q,
    float* __restrict__ p2, float* __restrict__ q2) {
  int wid  = threadIdx.x >> 6;
  int lane = threadIdx.x & 63;
  int row  = blockIdx.x * 4 + wid;  // 0..16383
  const float* X;
  float* out;
  int r;
  if (row < NROWS) { X = P; out = p2; r = row; }
  else             { X = Q; out = q2; r = row - NROWS; }
  float v = X[(size_t)r * DIM + lane];
  float s = wave_reduce_add(v * v);
  if (lane == 0) out[r] = s;
}

__global__ void init_u_kernel(float* __restrict__ u) {
  int i = blockIdx.x * blockDim.x + threadIdx.x;
  if (i < NROWS) u[i] = 1.0f / 64.0f;
}

// ---------- kgen: MFMA bf16, 128x128 tile, fp8 e5m2 via HW cvt_pk_bf8 ----------

struct KgenSmem {
  unsigned char A[128 * 128];   // -2P tile, bf16, swizzled
  unsigned char B[128 * 128];   // Q tile, bf16, swizzled
  float p2s[128];
  float q2s[128];
};

__device__ __forceinline__ int swiz_off(int row, int kc) {
  return row * 128 + ((kc ^ (row & 7)) << 4);
}

__global__ __launch_bounds__(256) void kgen_kernel(
    const float* __restrict__ P, const float* __restrict__ Q,
    const float* __restrict__ p2, const float* __restrict__ q2,
    unsigned char* __restrict__ K) {
  __shared__ KgenSmem sm;
  const int t  = threadIdx.x;
  const int bi = blockIdx.y * 128;
  const int bj = blockIdx.x * 128;

  {
    const float4* P4 = (const float4*)(P + (size_t)bi * DIM);
    const float4* Q4 = (const float4*)(Q + (size_t)bj * DIM);
    #pragma unroll
    for (int it = 0; it < 4; ++it) {
      int idx = t + it * 256;
      int row = idx >> 3;
      int kc  = idx & 7;
      int g   = row * 16 + kc * 2;
      float4 a0 = P4[g], a1 = P4[g + 1];
      float4 b0 = Q4[g], b1 = Q4[g + 1];
      uint4 pa, pb;
      pa.x = f2bf(-2.f * a0.x) | ((uint32_t)f2bf(-2.f * a0.y) << 16);
      pa.y = f2bf(-2.f * a0.z) | ((uint32_t)f2bf(-2.f * a0.w) << 16);
      pa.z = f2bf(-2.f * a1.x) | ((uint32_t)f2bf(-2.f * a1.y) << 16);
      pa.w = f2bf(-2.f * a1.z) | ((uint32_t)f2bf(-2.f * a1.w) << 16);
      pb.x = f2bf(b0.x) | ((uint32_t)f2bf(b0.y) << 16);
      pb.y = f2bf(b0.z) | ((uint32_t)f2bf(b0.w) << 16);
      pb.z = f2bf(b1.x) | ((uint32_t)f2bf(b1.y) << 16);
      pb.w = f2bf(b1.z) | ((uint32_t)f2bf(b1.w) << 16);
      *(uint4*)(sm.A + swiz_off(row, kc)) = pa;
      *(uint4*)(sm.B + swiz_off(row, kc)) = pb;
    }
    if (t < 128)                   sm.p2s[t]       = p2[bi + t];
    else                           sm.q2s[t - 128] = q2[bj + t - 128];
  }
  __syncthreads();

  const int w        = t >> 6;
  const int lane     = t & 63;
  const int quad     = lane >> 4;
  const int m16      = lane & 15;
  const int wave_row = (w >> 1) * 64;
  const int wave_col = (w & 1) * 64;

  float pn[4];
  f32x4 qn[4];
  #pragma unroll
  for (int ti = 0; ti < 4; ++ti) pn[ti] = sm.p2s[wave_row + ti * 16 + m16];
  #pragma unroll
  for (int tj = 0; tj < 4; ++tj)
    qn[tj] = *(const f32x4*)&sm.q2s[wave_col + tj * 16 + quad * 4];

  f32x4 acc[4][4];
  #pragma unroll
  for (int ti = 0; ti < 4; ++ti)
    #pragma unroll
    for (int tj = 0; tj < 4; ++tj) acc[ti][tj] = qn[tj] + pn[ti];

  #pragma unroll
  for (int kstep = 0; kstep < 2; ++kstep) {
    const int kc = kstep * 4 + quad;
    s16x8 af[4], bf[4];
    #pragma unroll
    for (int ti = 0; ti < 4; ++ti)
      af[ti] = *(const s16x8*)(sm.A + swiz_off(wave_row + ti * 16 + m16, kc));
    #pragma unroll
    for (int tj = 0; tj < 4; ++tj)
      bf[tj] = *(const s16x8*)(sm.B + swiz_off(wave_col + tj * 16 + m16, kc));
    #pragma unroll
    for (int ti = 0; ti < 4; ++ti)
      #pragma unroll
      for (int tj = 0; tj < 4; ++tj)
        acc[ti][tj] = __builtin_amdgcn_mfma_f32_16x16x32_bf16(
            bf[tj], af[ti], acc[ti][tj], 0, 0, 0);   // swapped operands
  }

  // epilogue: sq -> sqrt -> exp -> e5m2 via v_cvt_pk_bf8_f32 -> dword store
  #pragma unroll
  for (int ti = 0; ti < 4; ++ti) {
    unsigned char* rowp =
        K + (size_t)(bi + wave_row + ti * 16 + m16) * NROWS + bj + wave_col + quad * 4;
    #pragma unroll
    for (int tj = 0; tj < 4; ++tj) {
      f32x4 sq = acc[ti][tj];
      float k0 = __expf(-10.f * __builtin_amdgcn_sqrtf(fmaxf(sq.x, 0.f)));
      float k1 = __expf(-10.f * __builtin_amdgcn_sqrtf(fmaxf(sq.y, 0.f)));
      float k2 = __expf(-10.f * __builtin_amdgcn_sqrtf(fmaxf(sq.z, 0.f)));
      float k3 = __expf(-10.f * __builtin_amdgcn_sqrtf(fmaxf(sq.w, 0.f)));
      int pk = __builtin_amdgcn_cvt_pk_bf8_f32(k0, k1, 0, false);
      pk     = __builtin_amdgcn_cvt_pk_bf8_f32(k2, k3, pk, true);
      *(uint32_t*)(rowp + tj * 16) = (uint32_t)pk;
    }
  }
}

// ---------- cooperative persistent matvec: r7-proven body, 10 passes ----------
// 1024 blocks x 256 thr, 8 rows/block (2 per wave). Per pass: stage x to LDS as
// packed f16 pairs, each wave dots 2 full K rows (no K buffered across loop
// iters -> no spill pressure), grid.sync between passes. Pass 9 fuses the loss.

__global__ __launch_bounds__(256, 4) void sink10_kernel(
    const unsigned char* __restrict__ K, float* __restrict__ ub,
    float* __restrict__ vb, float* __restrict__ partials,
    float* __restrict__ out) {
  cg::grid_group grid = cg::this_grid();
  __shared__ uint32_t xsh[NROWS / 2];   // 16 KB packed f16 pairs
  __shared__ float sred[4];
  const int t    = threadIdx.x;
  const int lane = t & 63;
  const int w    = t >> 6;

  #pragma unroll 1
  for (int m = 0; m < 10; ++m) {
    if (m > 0) {
      grid.sync();                      // prev pass's y visible; xsh safe to reuse
      const float* xin = (m & 1) ? vb : ub;
      const float4* x4 = (const float4*)xin;
      #pragma unroll
      for (int i = 0; i < 8; ++i) {
        float4 xv = x4[t + i * 256];
        uint32_t lo = __builtin_bit_cast(uint32_t, __builtin_amdgcn_cvt_pkrtz(xv.x, xv.y));
        uint32_t hi = __builtin_bit_cast(uint32_t, __builtin_amdgcn_cvt_pkrtz(xv.z, xv.w));
        *(uint2*)&xsh[2 * t + 512 * i] = uint2{lo, hi};
      }
      __syncthreads();
    }

    float* yout = (m & 1) ? ub : vb;
    float wloss = 0.f;
    #pragma unroll 1
    for (int rr = 0; rr < 2; ++rr) {
      const int row = blockIdx.x * 8 + w * 2 + rr;
      const uint4* k4 = (const uint4*)(K + (size_t)row * NROWS);

      if (m == 0) {
        // u0 = 1/64 constant: s = sum K, y = 64/s
        const h2 one2 = (h2){(_Float16)1.f, (_Float16)1.f};
        float a0 = 0.f, a1 = 0.f;
        #pragma unroll
        for (int s = 0; s < 8; ++s) {
          uint4 kw = k4[s * 64 + lane];
          a0 = __builtin_amdgcn_fdot2(kpair(kw.x, SEL01), one2, a0, false);
          a1 = __builtin_amdgcn_fdot2(kpair(kw.x, SEL23), one2, a1, false);
          a0 = __builtin_amdgcn_fdot2(kpair(kw.y, SEL01), one2, a0, false);
          a1 = __builtin_amdgcn_fdot2(kpair(kw.y, SEL23), one2, a1, false);
          a0 = __builtin_amdgcn_fdot2(kpair(kw.z, SEL01), one2, a0, false);
          a1 = __builtin_amdgcn_fdot2(kpair(kw.z, SEL23), one2, a1, false);
          a0 = __builtin_amdgcn_fdot2(kpair(kw.w, SEL01), one2, a0, false);
          a1 = __builtin_amdgcn_fdot2(kpair(kw.w, SEL23), one2, a1, false);
        }
        float s = wave_reduce_add(a0 + a1);
        if (lane == 0) yout[row] = 64.f / s;
      } else if (m < 9) {
        float a0 = 0.f, a1 = 0.f, a2 = 0.f, a3 = 0.f;
        #pragma unroll
        for (int s = 0; s < 8; ++s) {
          uint4 kw = k4[s * 64 + lane];
          int base = (s * 64 + lane) * 8;
          uint4 xa = *(const uint4*)&xsh[base];
          uint4 xb = *(const uint4*)&xsh[base + 4];
          MV_DOT(kw.x, xa.x, xa.y, a0, a1)
          MV_DOT(kw.y, xa.z, xa.w, a2, a3)
          MV_DOT(kw.z, xb.x, xb.y, a0, a1)
          MV_DOT(kw.w, xb.z, xb.w, a2, a3)
        }
        float s = wave_reduce_add((a0 + a1) + (a2 + a3));
        if (lane == 0) yout[row] = 1.0f / s;
      } else {
        float s1 = 0.f, s2 = 0.f;
        #pragma unroll
        for (int s = 0; s < 8; ++s) {
          uint4 kw = k4[s * 64 + lane];
          int base = (s * 64 + lane) * 8;
          uint4 xa = *(const uint4*)&xsh[base];
          uint4 xb = *(const uint4*)&xsh[base + 4];
          FN_DOT(kw.x, xa.x, xa.y, s1, s2)
          FN_DOT(kw.y, xa.z, xa.w, s1, s2)
          FN_DOT(kw.z, xb.x, xb.y, s1, s2)
          FN_DOT(kw.w, xb.z, xb.w, s1, s2)
        }
        s1 = wave_reduce_add(s1);
        s2 = wave_reduce_add(s2);
        if (lane == 0) wloss += (-EPS) * s2 / s1;
      }
    }
    if (m == 9) {
      if (lane == 0) sred[w] = wloss;
      __syncthreads();
      if (t == 0) partials[blockIdx.x] = sred[0] + sred[1] + sred[2] + sred[3];
    }
  }

  grid.sync();
  if (blockIdx.x == 0) {
    float s = partials[t] + partials[t + 256] + partials[t + 512] + partials[t + 768];
    s = wave_reduce_add(s);
    __shared__ float fred[4];
    if (lane == 0) fred[w] = s;
    __syncthreads();
    if (t == 0) out[0] = fred[0] + fred[1] + fred[2] + fred[3];
  }
}

// ---------- fallback (non-cooperative) chain: r7-proven ----------

__global__ __launch_bounds__(256) void matvec8_kernel(
    const unsigned char* __restrict__ K, const float* __restrict__ x,
    float* __restrict__ y) {
  __shared__ uint32_t xsh[NROWS / 2];
  const int t    = threadIdx.x;
  const int lane = t & 63;
  const int w    = t >> 6;

  const float4* x4 = (const float4*)x;
  #pragma unroll
  for (int i = 0; i < 8; ++i) {
    float4 xv = x4[t + i * 256];
    uint32_t lo = __builtin_bit_cast(uint32_t, __builtin_amdgcn_cvt_pkrtz(xv.x, xv.y));
    uint32_t hi = __builtin_bit_cast(uint32_t, __builtin_amdgcn_cvt_pkrtz(xv.z, xv.w));
    *(uint2*)&xsh[2 * t + 512 * i] = uint2{lo, hi};
  }
  __syncthreads();

  #pragma unroll 1
  for (int rr = 0; rr < 2; ++rr) {
    const int row = blockIdx.x * 8 + w * 2 + rr;
    const uint4* k4 = (const uint4*)(K + (size_t)row * NROWS);
    float a0 = 0.f, a1 = 0.f, a2 = 0.f, a3 = 0.f;
    #pragma unroll
    for (int s = 0; s < 8; ++s) {
      uint4 kw = k4[s * 64 + lane];
      int base = (s * 64 + lane) * 8;
      uint4 xa = *(const uint4*)&xsh[base];
      uint4 xb = *(const uint4*)&xsh[base + 4];
      MV_DOT(kw.x, xa.x, xa.y, a0, a1)
      MV_DOT(kw.y, xa.z, xa.w, a2, a3)
      MV_DOT(kw.z, xb.x, xb.y, a0, a1)
      MV_DOT(kw.w, xb.z, xb.w, a2, a3)
    }
    float s = wave_reduce_add((a0 + a1) + (a2 + a3));
    if (lane == 0) y[row] = 1.0f / s;
  }
}

__global__ __launch_bounds__(256) void final8_kernel(
    const unsigned char* __restrict__ K, const float* __restrict__ v,
    float* __restrict__ partials) {
  __shared__ uint32_t xsh[NROWS / 2];
  __shared__ float sred[4];
  const int t    = threadIdx.x;
  const int lane = t & 63;
  const int w    = t >> 6;

  const float4* x4 = (const float4*)v;
  #pragma unroll
  for (int i = 0; i < 8; ++i) {
    float4 xv = x4[t + i * 256];
    uint32_t lo = __builtin_bit_cast(uint32_t, __builtin_amdgcn_cvt_pkrtz(xv.x, xv.y));
    uint32_t hi = __builtin_bit_cast(uint32_t, __builtin_amdgcn_cvt_pkrtz(xv.z, xv.w));
    *(uint2*)&xsh[2 * t + 512 * i] = uint2{lo, hi};
  }
  __syncthreads();

  float wloss = 0.f;
  #pragma unroll 1
  for (int rr = 0; rr < 2; ++rr) {
    const int row = blockIdx.x * 8 + w * 2 + rr;
    const uint4* k4 = (const uint4*)(K + (size_t)row * NROWS);
    float s1 = 0.f, s2 = 0.f;
    #pragma unroll
    for (int s = 0; s < 8; ++s) {
      uint4 kw = k4[s * 64 + lane];
      int base = (s * 64 + lane) * 8;
      uint4 xa = *(const uint4*)&xsh[base];
      uint4 xb = *(const uint4*)&xsh[base + 4];
      FN_DOT(kw.x, xa.x, xa.y, s1, s2)
      FN_DOT(kw.y, xa.z, xa.w, s1, s2)
      FN_DOT(kw.z, xb.x, xb.y, s1, s2)
      FN_DOT(kw.w, xb.z, xb.w, s1, s2)
    }
    s1 = wave_reduce_add(s1);
    s2 = wave_reduce_add(s2);
    if (lane == 0) wloss += (-EPS) * s2 / s1;
  }
  if (lane == 0) sred[w] = wloss;
  __syncthreads();
  if (t == 0) partials[blockIdx.x] = sred[0] + sred[1] + sred[2] + sred[3];
}

__global__ __launch_bounds__(256) void reduce_kernel(
    const float* __restrict__ partials, float* __restrict__ out) {
  const int t = threadIdx.x;
  float s = partials[t] + partials[t + 256] + partials[t + 512] + partials[t + 768];
  s = wave_reduce_add(s);
  __shared__ float red[4];
  int lane = t & 63, wid = t >> 6;
  if (lane == 0) red[wid] = s;
  __syncthreads();
  if (t == 0) out[0] = red[0] + red[1] + red[2] + red[3];
}

// ---------- launch ----------

extern "C" void kernel_launch(void* const* d_in, const int* in_sizes, int n_in,
                              void* d_out, int out_size, void* d_ws, size_t ws_size,
                              hipStream_t stream) {
  const float* P = (const float*)d_in[0];
  const float* Q = (const float*)d_in[1];
  float* out = (float*)d_out;

  char* ws = (char*)d_ws;
  unsigned char* K = (unsigned char*)ws;                 // 8192*8192 = 67108864 B
  float* p2 = (float*)(ws + (size_t)NROWS * NROWS);
  float* q2 = p2 + NROWS;
  float* ub = q2 + NROWS;
  float* vb = ub + NROWS;
  float* partials = vb + NROWS;                          // >= 1024 floats

  rownorm_kernel<<<(2 * NROWS) / 4, 256, 0, stream>>>(P, Q, p2, q2);
  kgen_kernel<<<dim3(NROWS / 128, NROWS / 128), 256, 0, stream>>>(P, Q, p2, q2, K);

  void* args[5] = {(void*)&K, (void*)&ub, (void*)&vb, (void*)&partials, (void*)&out};
  hipError_t err = hipLaunchCooperativeKernel((const void*)sink10_kernel,
                                              dim3(1024), dim3(256), args, 0, stream);
  if (err != hipSuccess) {
    // Deterministic fallback: r7 chain.
    init_u_kernel<<<NROWS / 256, 256, 0, stream>>>(ub);
    for (int m = 0; m < 9; ++m) {
      const float* xin = (m & 1) ? vb : ub;
      float* yout      = (m & 1) ? ub : vb;
      matvec8_kernel<<<NROWS / 8, 256, 0, stream>>>(K, xin, yout);
    }
    final8_kernel<<<NROWS / 8, 256, 0, stream>>>(K, vb, partials);
    reduce_kernel<<<1, 256, 0, stream>>>(partials, out);
  }
}

// Round 9
// 276.788 us; speedup vs baseline: 5.0842x; 5.0842x over previous
//
#include <hip/hip_runtime.h>
#include <hip/hip_fp16.h>
#include <stdint.h>

#define NROWS 8192
#define DIM 64
#define EPS 0.1f

typedef float f32x4 __attribute__((ext_vector_type(4)));
typedef short s16x8 __attribute__((ext_vector_type(8)));
typedef _Float16 h2 __attribute__((ext_vector_type(2)));

// ---------- helpers ----------

__device__ __forceinline__ float wave_reduce_add(float v) {
  #pragma unroll
  for (int off = 32; off > 0; off >>= 1) v += __shfl_down(v, off, 64);
  return v;
}

__device__ __forceinline__ unsigned short f2bf(float f) {
  uint32_t u = __float_as_uint(f);
  return (unsigned short)((u + 0x7fffu + ((u >> 16) & 1u)) >> 16);
}

// Packed f16 pair from two e5m2 bytes of wd (byte<<8 == exact f16).
#define SEL01 0x01040004u
#define SEL23 0x03040204u
__device__ __forceinline__ h2 kpair(uint32_t wd, uint32_t sel) {
  return __builtin_bit_cast(h2, __builtin_amdgcn_perm(0u, wd, sel));
}

#define MV_DOT(d, xlo, xhi, accA, accB)                                              \
  accA = __builtin_amdgcn_fdot2(kpair((d), SEL01), __builtin_bit_cast(h2, (xlo)),    \
                                accA, false);                                        \
  accB = __builtin_amdgcn_fdot2(kpair((d), SEL23), __builtin_bit_cast(h2, (xhi)),    \
                                accB, false);

#define FN_DOT(d, xlo, xhi, s1, s2)                                                  \
  {                                                                                  \
    h2 k01 = kpair((d), SEL01), k23 = kpair((d), SEL23);                             \
    h2 x01 = __builtin_bit_cast(h2, (xlo)), x23 = __builtin_bit_cast(h2, (xhi));     \
    s1 = __builtin_amdgcn_fdot2(k01, x01, s1, false);                                \
    s1 = __builtin_amdgcn_fdot2(k23, x23, s1, false);                                \
    float kk;                                                                        \
    kk = (float)k01.x; s2 = fmaf(kk * (float)x01.x, __logf(fmaxf(kk, 1e-7f)), s2);   \
    kk = (float)k01.y; s2 = fmaf(kk * (float)x01.y, __logf(fmaxf(kk, 1e-7f)), s2);   \
    kk = (float)k23.x; s2 = fmaf(kk * (float)x23.x, __logf(fmaxf(kk, 1e-7f)), s2);   \
    kk = (float)k23.y; s2 = fmaf(kk * (float)x23.y, __logf(fmaxf(kk, 1e-7f)), s2);   \
  }

// ---------- small kernels ----------

__global__ __launch_bounds__(256) void rownorm_kernel(
    const float* __restrict__ P, const float* __restrict__ Q,
    float* __restrict__ p2, float* __restrict__ q2) {
  int wid  = threadIdx.x >> 6;
  int lane = threadIdx.x & 63;
  int row  = blockIdx.x * 4 + wid;  // 0..16383
  const float* X;
  float* out;
  int r;
  if (row < NROWS) { X = P; out = p2; r = row; }
  else             { X = Q; out = q2; r = row - NROWS; }
  float v = X[(size_t)r * DIM + lane];
  float s = wave_reduce_add(v * v);
  if (lane == 0) out[r] = s;
}

// v1[i] = 64 / rowsum[i]  (u0 = 1/64 constant folded into kgen's rowsum)
__global__ void v1_kernel(const float* __restrict__ rowsum, float* __restrict__ vb) {
  int i = blockIdx.x * blockDim.x + threadIdx.x;
  if (i < NROWS) vb[i] = 64.0f / rowsum[i];
}

// ---------- kgen: MFMA bf16, 128x128 tile, e5m2 out + fused row sums ----------

struct KgenSmem {
  unsigned char A[128 * 128];   // -2P tile, bf16, swizzled
  unsigned char B[128 * 128];   // Q tile, bf16, swizzled
  float p2s[128];
  float q2s[128];
};

__device__ __forceinline__ int swiz_off(int row, int kc) {
  return row * 128 + ((kc ^ (row & 7)) << 4);
}

__global__ __launch_bounds__(256) void kgen_kernel(
    const float* __restrict__ P, const float* __restrict__ Q,
    const float* __restrict__ p2, const float* __restrict__ q2,
    unsigned char* __restrict__ K, float* __restrict__ rowsum) {
  __shared__ KgenSmem sm;
  const int t  = threadIdx.x;
  const int bi = blockIdx.y * 128;
  const int bj = blockIdx.x * 128;

  {
    const float4* P4 = (const float4*)(P + (size_t)bi * DIM);
    const float4* Q4 = (const float4*)(Q + (size_t)bj * DIM);
    #pragma unroll
    for (int it = 0; it < 4; ++it) {
      int idx = t + it * 256;
      int row = idx >> 3;
      int kc  = idx & 7;
      int g   = row * 16 + kc * 2;
      float4 a0 = P4[g], a1 = P4[g + 1];
      float4 b0 = Q4[g], b1 = Q4[g + 1];
      uint4 pa, pb;
      pa.x = f2bf(-2.f * a0.x) | ((uint32_t)f2bf(-2.f * a0.y) << 16);
      pa.y = f2bf(-2.f * a0.z) | ((uint32_t)f2bf(-2.f * a0.w) << 16);
      pa.z = f2bf(-2.f * a1.x) | ((uint32_t)f2bf(-2.f * a1.y) << 16);
      pa.w = f2bf(-2.f * a1.z) | ((uint32_t)f2bf(-2.f * a1.w) << 16);
      pb.x = f2bf(b0.x) | ((uint32_t)f2bf(b0.y) << 16);
      pb.y = f2bf(b0.z) | ((uint32_t)f2bf(b0.w) << 16);
      pb.z = f2bf(b1.x) | ((uint32_t)f2bf(b1.y) << 16);
      pb.w = f2bf(b1.z) | ((uint32_t)f2bf(b1.w) << 16);
      *(uint4*)(sm.A + swiz_off(row, kc)) = pa;
      *(uint4*)(sm.B + swiz_off(row, kc)) = pb;
    }
    if (t < 128)                   sm.p2s[t]       = p2[bi + t];
    else                           sm.q2s[t - 128] = q2[bj + t - 128];
  }
  __syncthreads();

  const int w        = t >> 6;
  const int lane     = t & 63;
  const int quad     = lane >> 4;
  const int m16      = lane & 15;
  const int wave_row = (w >> 1) * 64;
  const int wave_col = (w & 1) * 64;

  float pn[4];
  f32x4 qn[4];
  #pragma unroll
  for (int ti = 0; ti < 4; ++ti) pn[ti] = sm.p2s[wave_row + ti * 16 + m16];
  #pragma unroll
  for (int tj = 0; tj < 4; ++tj)
    qn[tj] = *(const f32x4*)&sm.q2s[wave_col + tj * 16 + quad * 4];

  f32x4 acc[4][4];
  #pragma unroll
  for (int ti = 0; ti < 4; ++ti)
    #pragma unroll
    for (int tj = 0; tj < 4; ++tj) acc[ti][tj] = qn[tj] + pn[ti];

  #pragma unroll
  for (int kstep = 0; kstep < 2; ++kstep) {
    const int kc = kstep * 4 + quad;
    s16x8 af[4], bf[4];
    #pragma unroll
    for (int ti = 0; ti < 4; ++ti)
      af[ti] = *(const s16x8*)(sm.A + swiz_off(wave_row + ti * 16 + m16, kc));
    #pragma unroll
    for (int tj = 0; tj < 4; ++tj)
      bf[tj] = *(const s16x8*)(sm.B + swiz_off(wave_col + tj * 16 + m16, kc));
    #pragma unroll
    for (int ti = 0; ti < 4; ++ti)
      #pragma unroll
      for (int tj = 0; tj < 4; ++tj)
        acc[ti][tj] = __builtin_amdgcn_mfma_f32_16x16x32_bf16(
            bf[tj], af[ti], acc[ti][tj], 0, 0, 0);   // swapped operands
  }

  // epilogue: sq -> sqrt -> exp -> e5m2 (v_cvt_pk_bf8) -> dword store,
  // plus per-row partial sums (row lives in the 4 quads of one wave).
  float rs[4] = {0.f, 0.f, 0.f, 0.f};
  #pragma unroll
  for (int ti = 0; ti < 4; ++ti) {
    unsigned char* rowp =
        K + (size_t)(bi + wave_row + ti * 16 + m16) * NROWS + bj + wave_col + quad * 4;
    #pragma unroll
    for (int tj = 0; tj < 4; ++tj) {
      f32x4 sq = acc[ti][tj];
      float k0 = __expf(-10.f * __builtin_amdgcn_sqrtf(fmaxf(sq.x, 0.f)));
      float k1 = __expf(-10.f * __builtin_amdgcn_sqrtf(fmaxf(sq.y, 0.f)));
      float k2 = __expf(-10.f * __builtin_amdgcn_sqrtf(fmaxf(sq.z, 0.f)));
      float k3 = __expf(-10.f * __builtin_amdgcn_sqrtf(fmaxf(sq.w, 0.f)));
      int pk = __builtin_amdgcn_cvt_pk_bf8_f32(k0, k1, 0, false);
      pk     = __builtin_amdgcn_cvt_pk_bf8_f32(k2, k3, pk, true);
      *(uint32_t*)(rowp + tj * 16) = (uint32_t)pk;
      rs[ti] += (k0 + k1) + (k2 + k3);
    }
  }
  // reduce across the 4 quads (same row) then one atomic per row per half-wave
  #pragma unroll
  for (int ti = 0; ti < 4; ++ti) {
    float v = rs[ti];
    v += __shfl_xor(v, 16, 64);
    v += __shfl_xor(v, 32, 64);
    if (quad == 0) atomicAdd(&rowsum[bi + wave_row + ti * 16 + m16], v);
  }
}

// ---------- matvec8: 8 rows/block, rr-unrolled (both rows' K in flight) ----------

__global__ __launch_bounds__(256) void matvec8_kernel(
    const unsigned char* __restrict__ K, const float* __restrict__ x,
    float* __restrict__ y) {
  __shared__ uint32_t xsh[NROWS / 2];   // 16 KB packed f16 pairs
  const int t    = threadIdx.x;
  const int lane = t & 63;
  const int w    = t >> 6;

  const float4* x4 = (const float4*)x;
  #pragma unroll
  for (int i = 0; i < 8; ++i) {
    float4 xv = x4[t + i * 256];
    uint32_t lo = __builtin_bit_cast(uint32_t, __builtin_amdgcn_cvt_pkrtz(xv.x, xv.y));
    uint32_t hi = __builtin_bit_cast(uint32_t, __builtin_amdgcn_cvt_pkrtz(xv.z, xv.w));
    *(uint2*)&xsh[2 * t + 512 * i] = uint2{lo, hi};
  }
  __syncthreads();

  const int row0 = blockIdx.x * 8 + w * 2;
  const uint4* k40 = (const uint4*)(K + (size_t)row0 * NROWS);
  const uint4* k41 = (const uint4*)(K + (size_t)(row0 + 1) * NROWS);
  uint4 kw0[8], kw1[8];
  #pragma unroll
  for (int s = 0; s < 8; ++s) kw0[s] = k40[s * 64 + lane];
  #pragma unroll
  for (int s = 0; s < 8; ++s) kw1[s] = k41[s * 64 + lane];

  float a0 = 0.f, a1 = 0.f, a2 = 0.f, a3 = 0.f;
  float b0 = 0.f, b1 = 0.f, b2 = 0.f, b3 = 0.f;
  #pragma unroll
  for (int s = 0; s < 8; ++s) {
    int base = (s * 64 + lane) * 8;
    uint4 xa = *(const uint4*)&xsh[base];
    uint4 xb = *(const uint4*)&xsh[base + 4];
    MV_DOT(kw0[s].x, xa.x, xa.y, a0, a1)
    MV_DOT(kw0[s].y, xa.z, xa.w, a2, a3)
    MV_DOT(kw0[s].z, xb.x, xb.y, a0, a1)
    MV_DOT(kw0[s].w, xb.z, xb.w, a2, a3)
    MV_DOT(kw1[s].x, xa.x, xa.y, b0, b1)
    MV_DOT(kw1[s].y, xa.z, xa.w, b2, b3)
    MV_DOT(kw1[s].z, xb.x, xb.y, b0, b1)
    MV_DOT(kw1[s].w, xb.z, xb.w, b2, b3)
  }
  float s0 = wave_reduce_add((a0 + a1) + (a2 + a3));
  float s1 = wave_reduce_add((b0 + b1) + (b2 + b3));
  if (lane == 0) {
    y[row0]     = 1.0f / s0;
    y[row0 + 1] = 1.0f / s1;
  }
}

// ---------- final8: fused 10th matvec + loss, 8 rows/block ----------

__global__ __launch_bounds__(256) void final8_kernel(
    const unsigned char* __restrict__ K, const float* __restrict__ v,
    float* __restrict__ partials) {
  __shared__ uint32_t xsh[NROWS / 2];
  __shared__ float sred[4];
  const int t    = threadIdx.x;
  const int lane = t & 63;
  const int w    = t >> 6;

  const float4* x4 = (const float4*)v;
  #pragma unroll
  for (int i = 0; i < 8; ++i) {
    float4 xv = x4[t + i * 256];
    uint32_t lo = __builtin_bit_cast(uint32_t, __builtin_amdgcn_cvt_pkrtz(xv.x, xv.y));
    uint32_t hi = __builtin_bit_cast(uint32_t, __builtin_amdgcn_cvt_pkrtz(xv.z, xv.w));
    *(uint2*)&xsh[2 * t + 512 * i] = uint2{lo, hi};
  }
  __syncthreads();

  float wloss = 0.f;
  #pragma unroll 1
  for (int rr = 0; rr < 2; ++rr) {
    const int row = blockIdx.x * 8 + w * 2 + rr;
    const uint4* k4 = (const uint4*)(K + (size_t)row * NROWS);
    float s1 = 0.f, s2 = 0.f;
    #pragma unroll
    for (int s = 0; s < 8; ++s) {
      uint4 kw = k4[s * 64 + lane];
      int base = (s * 64 + lane) * 8;
      uint4 xa = *(const uint4*)&xsh[base];
      uint4 xb = *(const uint4*)&xsh[base + 4];
      FN_DOT(kw.x, xa.x, xa.y, s1, s2)
      FN_DOT(kw.y, xa.z, xa.w, s1, s2)
      FN_DOT(kw.z, xb.x, xb.y, s1, s2)
      FN_DOT(kw.w, xb.z, xb.w, s1, s2)
    }
    s1 = wave_reduce_add(s1);
    s2 = wave_reduce_add(s2);
    if (lane == 0) wloss += (-EPS) * s2 / s1;
  }
  if (lane == 0) sred[w] = wloss;
  __syncthreads();
  if (t == 0) partials[blockIdx.x] = sred[0] + sred[1] + sred[2] + sred[3];
}

// Sum 1024 partials -> out[0].
__global__ __launch_bounds__(256) void reduce_kernel(
    const float* __restrict__ partials, float* __restrict__ out) {
  const int t = threadIdx.x;
  float s = partials[t] + partials[t + 256] + partials[t + 512] + partials[t + 768];
  s = wave_reduce_add(s);
  __shared__ float red[4];
  int lane = t & 63, wid = t >> 6;
  if (lane == 0) red[wid] = s;
  __syncthreads();
  if (t == 0) out[0] = red[0] + red[1] + red[2] + red[3];
}

// ---------- launch ----------

extern "C" void kernel_launch(void* const* d_in, const int* in_sizes, int n_in,
                              void* d_out, int out_size, void* d_ws, size_t ws_size,
                              hipStream_t stream) {
  const float* P = (const float*)d_in[0];
  const float* Q = (const float*)d_in[1];
  float* out = (float*)d_out;

  char* ws = (char*)d_ws;
  unsigned char* K = (unsigned char*)ws;                 // 8192*8192 = 67108864 B
  float* p2 = (float*)(ws + (size_t)NROWS * NROWS);
  float* q2 = p2 + NROWS;
  float* ub = q2 + NROWS;
  float* vb = ub + NROWS;
  float* partials = vb + NROWS;                          // 1024 floats (pad to 8192)
  float* rowsum   = partials + NROWS;                    // 8192 floats

  rownorm_kernel<<<(2 * NROWS) / 4, 256, 0, stream>>>(P, Q, p2, q2);
  hipMemsetAsync(rowsum, 0, NROWS * sizeof(float), stream);
  kgen_kernel<<<dim3(NROWS / 128, NROWS / 128), 256, 0, stream>>>(P, Q, p2, q2, K, rowsum);
  v1_kernel<<<NROWS / 256, 256, 0, stream>>>(rowsum, vb);

  // Passes m=1..8 (m=0 fused into kgen rowsum): after m=8, vb holds v5.
  for (int m = 1; m < 9; ++m) {
    const float* xin = (m & 1) ? vb : ub;
    float* yout      = (m & 1) ? ub : vb;
    matvec8_kernel<<<NROWS / 8, 256, 0, stream>>>(K, xin, yout);
  }

  final8_kernel<<<NROWS / 8, 256, 0, stream>>>(K, vb, partials);
  reduce_kernel<<<1, 256, 0, stream>>>(partials, out);
}

// Round 10
// 260.631 us; speedup vs baseline: 5.3994x; 1.0620x over previous
//
#include <hip/hip_runtime.h>
#include <hip/hip_fp16.h>
#include <stdint.h>

#define NROWS 8192
#define DIM 64
#define EPS 0.1f

typedef float f32x4 __attribute__((ext_vector_type(4)));
typedef short s16x8 __attribute__((ext_vector_type(8)));
typedef _Float16 h2 __attribute__((ext_vector_type(2)));

// ---------- helpers ----------

__device__ __forceinline__ float wave_reduce_add(float v) {
  #pragma unroll
  for (int off = 32; off > 0; off >>= 1) v += __shfl_down(v, off, 64);
  return v;
}

__device__ __forceinline__ unsigned short f2bf(float f) {
  uint32_t u = __float_as_uint(f);
  return (unsigned short)((u + 0x7fffu + ((u >> 16) & 1u)) >> 16);
}

// Packed f16 pair from two e5m2 bytes of wd (byte<<8 == exact f16).
#define SEL01 0x01040004u
#define SEL23 0x03040204u
__device__ __forceinline__ h2 kpair(uint32_t wd, uint32_t sel) {
  return __builtin_bit_cast(h2, __builtin_amdgcn_perm(0u, wd, sel));
}

#define MV_DOT(d, xlo, xhi, accA, accB)                                              \
  accA = __builtin_amdgcn_fdot2(kpair((d), SEL01), __builtin_bit_cast(h2, (xlo)),    \
                                accA, false);                                        \
  accB = __builtin_amdgcn_fdot2(kpair((d), SEL23), __builtin_bit_cast(h2, (xhi)),    \
                                accB, false);

#define FN_DOT(d, xlo, xhi, s1, s2)                                                  \
  {                                                                                  \
    h2 k01 = kpair((d), SEL01), k23 = kpair((d), SEL23);                             \
    h2 x01 = __builtin_bit_cast(h2, (xlo)), x23 = __builtin_bit_cast(h2, (xhi));     \
    s1 = __builtin_amdgcn_fdot2(k01, x01, s1, false);                                \
    s1 = __builtin_amdgcn_fdot2(k23, x23, s1, false);                                \
    float kk;                                                                        \
    kk = (float)k01.x; s2 = fmaf(kk * (float)x01.x, __logf(fmaxf(kk, 1e-7f)), s2);   \
    kk = (float)k01.y; s2 = fmaf(kk * (float)x01.y, __logf(fmaxf(kk, 1e-7f)), s2);   \
    kk = (float)k23.x; s2 = fmaf(kk * (float)x23.x, __logf(fmaxf(kk, 1e-7f)), s2);   \
    kk = (float)k23.y; s2 = fmaf(kk * (float)x23.y, __logf(fmaxf(kk, 1e-7f)), s2);   \
  }

// ---------- small kernels ----------

__global__ __launch_bounds__(256) void rownorm_kernel(
    const float* __restrict__ P, const float* __restrict__ Q,
    float* __restrict__ p2, float* __restrict__ q2,
    float* __restrict__ rowsum) {
  int wid  = threadIdx.x >> 6;
  int lane = threadIdx.x & 63;
  int row  = blockIdx.x * 4 + wid;  // 0..16383
  const float* X;
  float* out;
  int r;
  if (row < NROWS) { X = P; out = p2; r = row; }
  else             { X = Q; out = q2; r = row - NROWS; }
  float v = X[(size_t)r * DIM + lane];
  float s = wave_reduce_add(v * v);
  if (lane == 0) out[r] = s;
  if (row < NROWS && lane == 1) rowsum[r] = 0.f;   // zero for kgen's atomics
}

// v1[i] = 64 / rowsum[i]  (u0 = 1/64 constant folded into kgen's rowsum)
__global__ void v1_kernel(const float* __restrict__ rowsum, float* __restrict__ vb) {
  int i = blockIdx.x * blockDim.x + threadIdx.x;
  if (i < NROWS) vb[i] = 64.0f / rowsum[i];
}

// ---------- kgen: MFMA bf16, 128x128 tile, e5m2 out + fused row sums ----------
// Epilogue does an in-register 4x4 transpose across quads so stores are
// dwordx4 with 64B-per-row segments (16 full cache lines per instruction).

struct KgenSmem {
  unsigned char A[128 * 128];   // -2P tile, bf16, swizzled
  unsigned char B[128 * 128];   // Q tile, bf16, swizzled
  float p2s[128];
  float q2s[128];
};

__device__ __forceinline__ int swiz_off(int row, int kc) {
  return row * 128 + ((kc ^ (row & 7)) << 4);
}

__global__ __launch_bounds__(256) void kgen_kernel(
    const float* __restrict__ P, const float* __restrict__ Q,
    const float* __restrict__ p2, const float* __restrict__ q2,
    unsigned char* __restrict__ K, float* __restrict__ rowsum) {
  __shared__ KgenSmem sm;
  const int t  = threadIdx.x;
  const int bi = blockIdx.y * 128;
  const int bj = blockIdx.x * 128;

  {
    const float4* P4 = (const float4*)(P + (size_t)bi * DIM);
    const float4* Q4 = (const float4*)(Q + (size_t)bj * DIM);
    #pragma unroll
    for (int it = 0; it < 4; ++it) {
      int idx = t + it * 256;
      int row = idx >> 3;
      int kc  = idx & 7;
      int g   = row * 16 + kc * 2;
      float4 a0 = P4[g], a1 = P4[g + 1];
      float4 b0 = Q4[g], b1 = Q4[g + 1];
      uint4 pa, pb;
      pa.x = f2bf(-2.f * a0.x) | ((uint32_t)f2bf(-2.f * a0.y) << 16);
      pa.y = f2bf(-2.f * a0.z) | ((uint32_t)f2bf(-2.f * a0.w) << 16);
      pa.z = f2bf(-2.f * a1.x) | ((uint32_t)f2bf(-2.f * a1.y) << 16);
      pa.w = f2bf(-2.f * a1.z) | ((uint32_t)f2bf(-2.f * a1.w) << 16);
      pb.x = f2bf(b0.x) | ((uint32_t)f2bf(b0.y) << 16);
      pb.y = f2bf(b0.z) | ((uint32_t)f2bf(b0.w) << 16);
      pb.z = f2bf(b1.x) | ((uint32_t)f2bf(b1.y) << 16);
      pb.w = f2bf(b1.z) | ((uint32_t)f2bf(b1.w) << 16);
      *(uint4*)(sm.A + swiz_off(row, kc)) = pa;
      *(uint4*)(sm.B + swiz_off(row, kc)) = pb;
    }
    if (t < 128)                   sm.p2s[t]       = p2[bi + t];
    else                           sm.q2s[t - 128] = q2[bj + t - 128];
  }
  __syncthreads();

  const int w        = t >> 6;
  const int lane     = t & 63;
  const int quad     = lane >> 4;
  const int m16      = lane & 15;
  const int wave_row = (w >> 1) * 64;
  const int wave_col = (w & 1) * 64;

  float pn[4];
  f32x4 qn[4];
  #pragma unroll
  for (int ti = 0; ti < 4; ++ti) pn[ti] = sm.p2s[wave_row + ti * 16 + m16];
  #pragma unroll
  for (int tj = 0; tj < 4; ++tj)
    qn[tj] = *(const f32x4*)&sm.q2s[wave_col + tj * 16 + quad * 4];

  f32x4 acc[4][4];
  #pragma unroll
  for (int ti = 0; ti < 4; ++ti)
    #pragma unroll
    for (int tj = 0; tj < 4; ++tj) acc[ti][tj] = qn[tj] + pn[ti];

  #pragma unroll
  for (int kstep = 0; kstep < 2; ++kstep) {
    const int kc = kstep * 4 + quad;
    s16x8 af[4], bf[4];
    #pragma unroll
    for (int ti = 0; ti < 4; ++ti)
      af[ti] = *(const s16x8*)(sm.A + swiz_off(wave_row + ti * 16 + m16, kc));
    #pragma unroll
    for (int tj = 0; tj < 4; ++tj)
      bf[tj] = *(const s16x8*)(sm.B + swiz_off(wave_col + tj * 16 + m16, kc));
    #pragma unroll
    for (int ti = 0; ti < 4; ++ti)
      #pragma unroll
      for (int tj = 0; tj < 4; ++tj)
        acc[ti][tj] = __builtin_amdgcn_mfma_f32_16x16x32_bf16(
            bf[tj], af[ti], acc[ti][tj], 0, 0, 0);   // swapped operands
  }

  // epilogue: sq -> sqrt -> exp -> e5m2 pack; quad-transpose; dwordx4 store.
  float rs[4] = {0.f, 0.f, 0.f, 0.f};
  #pragma unroll
  for (int ti = 0; ti < 4; ++ti) {
    uint32_t a[4];
    #pragma unroll
    for (int tj = 0; tj < 4; ++tj) {
      f32x4 sq = acc[ti][tj];
      float k0 = __expf(-10.f * __builtin_amdgcn_sqrtf(fmaxf(sq.x, 0.f)));
      float k1 = __expf(-10.f * __builtin_amdgcn_sqrtf(fmaxf(sq.y, 0.f)));
      float k2 = __expf(-10.f * __builtin_amdgcn_sqrtf(fmaxf(sq.z, 0.f)));
      float k3 = __expf(-10.f * __builtin_amdgcn_sqrtf(fmaxf(sq.w, 0.f)));
      int pk = __builtin_amdgcn_cvt_pk_bf8_f32(k0, k1, 0, false);
      pk     = __builtin_amdgcn_cvt_pk_bf8_f32(k2, k3, pk, true);
      a[tj] = (uint32_t)pk;
      rs[ti] += (k0 + k1) + (k2 + k3);
    }
    // 4x4 transpose across quads: dest lane q, slot s <- src lane s, slot q.
    {
      uint32_t t0 = (uint32_t)__shfl_xor((int)a[1], 16, 64);
      uint32_t t1 = (uint32_t)__shfl_xor((int)a[0], 16, 64);
      uint32_t t2 = (uint32_t)__shfl_xor((int)a[3], 16, 64);
      uint32_t t3 = (uint32_t)__shfl_xor((int)a[2], 16, 64);
      bool o = (quad & 1);
      a[0] = o ? t0 : a[0];
      a[1] = o ? a[1] : t1;
      a[2] = o ? t2 : a[2];
      a[3] = o ? a[3] : t3;
      uint32_t u0 = (uint32_t)__shfl_xor((int)a[2], 32, 64);
      uint32_t u1 = (uint32_t)__shfl_xor((int)a[3], 32, 64);
      uint32_t u2 = (uint32_t)__shfl_xor((int)a[0], 32, 64);
      uint32_t u3 = (uint32_t)__shfl_xor((int)a[1], 32, 64);
      bool h = (quad & 2);
      a[0] = h ? u0 : a[0];
      a[1] = h ? u1 : a[1];
      a[2] = h ? a[2] : u2;
      a[3] = h ? a[3] : u3;
    }
    // lane (quad,m16) now holds 16 contiguous bytes of row (wave_row+ti*16+m16)
    // at col wave_col + quad*16 -> per instr: 16 rows x 64B full lines.
    uint4 v4 = uint4{a[0], a[1], a[2], a[3]};
    *(uint4*)(K + (size_t)(bi + wave_row + ti * 16 + m16) * NROWS +
              bj + wave_col + quad * 16) = v4;
  }
  // reduce across the 4 quads (same row) then one atomic per row per half-wave
  #pragma unroll
  for (int ti = 0; ti < 4; ++ti) {
    float v = rs[ti];
    v += __shfl_xor(v, 16, 64);
    v += __shfl_xor(v, 32, 64);
    if (quad == 0) atomicAdd(&rowsum[bi + wave_row + ti * 16 + m16], v);
  }
}

// ---------- matvec8: r7-proven form — 8 rows/block, 2 rows/wave loop ----------

__global__ __launch_bounds__(256) void matvec8_kernel(
    const unsigned char* __restrict__ K, const float* __restrict__ x,
    float* __restrict__ y) {
  __shared__ uint32_t xsh[NROWS / 2];   // 16 KB packed f16 pairs
  const int t    = threadIdx.x;
  const int lane = t & 63;
  const int w    = t >> 6;

  const float4* x4 = (const float4*)x;
  #pragma unroll
  for (int i = 0; i < 8; ++i) {
    float4 xv = x4[t + i * 256];
    uint32_t lo = __builtin_bit_cast(uint32_t, __builtin_amdgcn_cvt_pkrtz(xv.x, xv.y));
    uint32_t hi = __builtin_bit_cast(uint32_t, __builtin_amdgcn_cvt_pkrtz(xv.z, xv.w));
    *(uint2*)&xsh[2 * t + 512 * i] = uint2{lo, hi};
  }
  __syncthreads();

  #pragma unroll 1
  for (int rr = 0; rr < 2; ++rr) {
    const int row = blockIdx.x * 8 + w * 2 + rr;
    const uint4* k4 = (const uint4*)(K + (size_t)row * NROWS);
    float a0 = 0.f, a1 = 0.f, a2 = 0.f, a3 = 0.f;
    #pragma unroll
    for (int s = 0; s < 8; ++s) {
      uint4 kw = k4[s * 64 + lane];
      int base = (s * 64 + lane) * 8;
      uint4 xa = *(const uint4*)&xsh[base];
      uint4 xb = *(const uint4*)&xsh[base + 4];
      MV_DOT(kw.x, xa.x, xa.y, a0, a1)
      MV_DOT(kw.y, xa.z, xa.w, a2, a3)
      MV_DOT(kw.z, xb.x, xb.y, a0, a1)
      MV_DOT(kw.w, xb.z, xb.w, a2, a3)
    }
    float s = wave_reduce_add((a0 + a1) + (a2 + a3));
    if (lane == 0) y[row] = 1.0f / s;
  }
}

// ---------- final8: fused 10th matvec + loss, 8 rows/block ----------

__global__ __launch_bounds__(256) void final8_kernel(
    const unsigned char* __restrict__ K, const float* __restrict__ v,
    float* __restrict__ partials) {
  __shared__ uint32_t xsh[NROWS / 2];
  __shared__ float sred[4];
  const int t    = threadIdx.x;
  const int lane = t & 63;
  const int w    = t >> 6;

  const float4* x4 = (const float4*)v;
  #pragma unroll
  for (int i = 0; i < 8; ++i) {
    float4 xv = x4[t + i * 256];
    uint32_t lo = __builtin_bit_cast(uint32_t, __builtin_amdgcn_cvt_pkrtz(xv.x, xv.y));
    uint32_t hi = __builtin_bit_cast(uint32_t, __builtin_amdgcn_cvt_pkrtz(xv.z, xv.w));
    *(uint2*)&xsh[2 * t + 512 * i] = uint2{lo, hi};
  }
  __syncthreads();

  float wloss = 0.f;
  #pragma unroll 1
  for (int rr = 0; rr < 2; ++rr) {
    const int row = blockIdx.x * 8 + w * 2 + rr;
    const uint4* k4 = (const uint4*)(K + (size_t)row * NROWS);
    float s1 = 0.f, s2 = 0.f;
    #pragma unroll
    for (int s = 0; s < 8; ++s) {
      uint4 kw = k4[s * 64 + lane];
      int base = (s * 64 + lane) * 8;
      uint4 xa = *(const uint4*)&xsh[base];
      uint4 xb = *(const uint4*)&xsh[base + 4];
      FN_DOT(kw.x, xa.x, xa.y, s1, s2)
      FN_DOT(kw.y, xa.z, xa.w, s1, s2)
      FN_DOT(kw.z, xb.x, xb.y, s1, s2)
      FN_DOT(kw.w, xb.z, xb.w, s1, s2)
    }
    s1 = wave_reduce_add(s1);
    s2 = wave_reduce_add(s2);
    if (lane == 0) wloss += (-EPS) * s2 / s1;
  }
  if (lane == 0) sred[w] = wloss;
  __syncthreads();
  if (t == 0) partials[blockIdx.x] = sred[0] + sred[1] + sred[2] + sred[3];
}

// Sum 1024 partials -> out[0].
__global__ __launch_bounds__(256) void reduce_kernel(
    const float* __restrict__ partials, float* __restrict__ out) {
  const int t = threadIdx.x;
  float s = partials[t] + partials[t + 256] + partials[t + 512] + partials[t + 768];
  s = wave_reduce_add(s);
  __shared__ float red[4];
  int lane = t & 63, wid = t >> 6;
  if (lane == 0) red[wid] = s;
  __syncthreads();
  if (t == 0) out[0] = red[0] + red[1] + red[2] + red[3];
}

// ---------- launch ----------

extern "C" void kernel_launch(void* const* d_in, const int* in_sizes, int n_in,
                              void* d_out, int out_size, void* d_ws, size_t ws_size,
                              hipStream_t stream) {
  const float* P = (const float*)d_in[0];
  const float* Q = (const float*)d_in[1];
  float* out = (float*)d_out;

  char* ws = (char*)d_ws;
  unsigned char* K = (unsigned char*)ws;                 // 8192*8192 = 67108864 B
  float* p2 = (float*)(ws + (size_t)NROWS * NROWS);
  float* q2 = p2 + NROWS;
  float* ub = q2 + NROWS;
  float* vb = ub + NROWS;
  float* partials = vb + NROWS;                          // 1024 floats (pad to 8192)
  float* rowsum   = partials + NROWS;                    // 8192 floats

  rownorm_kernel<<<(2 * NROWS) / 4, 256, 0, stream>>>(P, Q, p2, q2, rowsum);
  kgen_kernel<<<dim3(NROWS / 128, NROWS / 128), 256, 0, stream>>>(P, Q, p2, q2, K, rowsum);
  v1_kernel<<<NROWS / 256, 256, 0, stream>>>(rowsum, vb);

  // Passes m=1..8 (m=0 fused into kgen rowsum): after m=8, vb holds v5.
  for (int m = 1; m < 9; ++m) {
    const float* xin = (m & 1) ? vb : ub;
    float* yout      = (m & 1) ? ub : vb;
    matvec8_kernel<<<NROWS / 8, 256, 0, stream>>>(K, xin, yout);
  }

  final8_kernel<<<NROWS / 8, 256, 0, stream>>>(K, vb, partials);
  reduce_kernel<<<1, 256, 0, stream>>>(partials, out);
}

// Round 11
// 251.936 us; speedup vs baseline: 5.5857x; 1.0345x over previous
//
#include <hip/hip_runtime.h>
#include <hip/hip_fp16.h>
#include <stdint.h>

#define NROWS 8192
#define DIM 64
#define EPS 0.1f

typedef float f32x4 __attribute__((ext_vector_type(4)));
typedef short s16x8 __attribute__((ext_vector_type(8)));
typedef _Float16 h2 __attribute__((ext_vector_type(2)));

// ---------- helpers ----------

__device__ __forceinline__ float wave_reduce_add(float v) {
  #pragma unroll
  for (int off = 32; off > 0; off >>= 1) v += __shfl_down(v, off, 64);
  return v;
}

// pack two fp32 -> bf16x2 dword by truncation (1 v_perm); x -> low, y -> high.
__device__ __forceinline__ uint32_t pack_bf16_trunc(float x, float y) {
  return __builtin_amdgcn_perm(__float_as_uint(y), __float_as_uint(x), 0x07060302u);
}

// Packed f16 pair from two e5m2 bytes of wd (byte<<8 == exact f16).
#define SEL01 0x01040004u
#define SEL23 0x03040204u
__device__ __forceinline__ h2 kpair(uint32_t wd, uint32_t sel) {
  return __builtin_bit_cast(h2, __builtin_amdgcn_perm(0u, wd, sel));
}

#define MV_DOT(d, xlo, xhi, accA, accB)                                              \
  accA = __builtin_amdgcn_fdot2(kpair((d), SEL01), __builtin_bit_cast(h2, (xlo)),    \
                                accA, false);                                        \
  accB = __builtin_amdgcn_fdot2(kpair((d), SEL23), __builtin_bit_cast(h2, (xhi)),    \
                                accB, false);

#define FN_DOT(d, xlo, xhi, s1, s2)                                                  \
  {                                                                                  \
    h2 k01 = kpair((d), SEL01), k23 = kpair((d), SEL23);                             \
    h2 x01 = __builtin_bit_cast(h2, (xlo)), x23 = __builtin_bit_cast(h2, (xhi));     \
    s1 = __builtin_amdgcn_fdot2(k01, x01, s1, false);                                \
    s1 = __builtin_amdgcn_fdot2(k23, x23, s1, false);                                \
    float kk;                                                                        \
    kk = (float)k01.x; s2 = fmaf(kk * (float)x01.x, __logf(fmaxf(kk, 1e-7f)), s2);   \
    kk = (float)k01.y; s2 = fmaf(kk * (float)x01.y, __logf(fmaxf(kk, 1e-7f)), s2);   \
    kk = (float)k23.x; s2 = fmaf(kk * (float)x23.x, __logf(fmaxf(kk, 1e-7f)), s2);   \
    kk = (float)k23.y; s2 = fmaf(kk * (float)x23.y, __logf(fmaxf(kk, 1e-7f)), s2);   \
  }

// ---------- small kernels ----------

__global__ __launch_bounds__(256) void rownorm_kernel(
    const float* __restrict__ P, const float* __restrict__ Q,
    float* __restrict__ p2, float* __restrict__ q2,
    float* __restrict__ rowsum) {
  int wid  = threadIdx.x >> 6;
  int lane = threadIdx.x & 63;
  int row  = blockIdx.x * 4 + wid;  // 0..16383
  const float* X;
  float* out;
  int r;
  if (row < NROWS) { X = P; out = p2; r = row; }
  else             { X = Q; out = q2; r = row - NROWS; }
  float v = X[(size_t)r * DIM + lane];
  float s = wave_reduce_add(v * v);
  if (lane == 0) out[r] = s;
  if (row < NROWS && lane == 1) rowsum[r] = 0.f;   // zero for kgen's atomics
}

// v1[i] = 64 / rowsum[i]  (u0 = 1/64 constant folded into kgen's rowsum)
__global__ void v1_kernel(const float* __restrict__ rowsum, float* __restrict__ vb) {
  int i = blockIdx.x * blockDim.x + threadIdx.x;
  if (i < NROWS) vb[i] = 64.0f / rowsum[i];
}

// ---------- kgen: MFMA bf16, 128x128 tile, e5m2 out + fused row sums ----------

struct KgenSmem {
  unsigned char A[128 * 128];   // -2P tile, bf16, swizzled
  unsigned char B[128 * 128];   // Q tile, bf16, swizzled
  float p2s[128];
  float q2s[128];
};

__device__ __forceinline__ int swiz_off(int row, int kc) {
  return row * 128 + ((kc ^ (row & 7)) << 4);
}

__global__ __launch_bounds__(256) void kgen_kernel(
    const float* __restrict__ P, const float* __restrict__ Q,
    const float* __restrict__ p2, const float* __restrict__ q2,
    unsigned char* __restrict__ K, float* __restrict__ rowsum) {
  __shared__ KgenSmem sm;
  const int t  = threadIdx.x;
  const int bi = blockIdx.y * 128;
  const int bj = blockIdx.x * 128;

  {
    const float4* P4 = (const float4*)(P + (size_t)bi * DIM);
    const float4* Q4 = (const float4*)(Q + (size_t)bj * DIM);
    #pragma unroll
    for (int it = 0; it < 4; ++it) {
      int idx = t + it * 256;
      int row = idx >> 3;
      int kc  = idx & 7;
      int g   = row * 16 + kc * 2;
      float4 a0 = P4[g], a1 = P4[g + 1];
      float4 b0 = Q4[g], b1 = Q4[g + 1];
      uint4 pa, pb;
      pa.x = pack_bf16_trunc(-2.f * a0.x, -2.f * a0.y);
      pa.y = pack_bf16_trunc(-2.f * a0.z, -2.f * a0.w);
      pa.z = pack_bf16_trunc(-2.f * a1.x, -2.f * a1.y);
      pa.w = pack_bf16_trunc(-2.f * a1.z, -2.f * a1.w);
      pb.x = pack_bf16_trunc(b0.x, b0.y);
      pb.y = pack_bf16_trunc(b0.z, b0.w);
      pb.z = pack_bf16_trunc(b1.x, b1.y);
      pb.w = pack_bf16_trunc(b1.z, b1.w);
      *(uint4*)(sm.A + swiz_off(row, kc)) = pa;
      *(uint4*)(sm.B + swiz_off(row, kc)) = pb;
    }
    if (t < 128)                   sm.p2s[t]       = p2[bi + t];
    else                           sm.q2s[t - 128] = q2[bj + t - 128];
  }
  __syncthreads();

  const int w        = t >> 6;
  const int lane     = t & 63;
  const int quad     = lane >> 4;
  const int m16      = lane & 15;
  const int wave_row = (w >> 1) * 64;
  const int wave_col = (w & 1) * 64;

  float pn[4];
  f32x4 qn[4];
  #pragma unroll
  for (int ti = 0; ti < 4; ++ti) pn[ti] = sm.p2s[wave_row + ti * 16 + m16];
  #pragma unroll
  for (int tj = 0; tj < 4; ++tj)
    qn[tj] = *(const f32x4*)&sm.q2s[wave_col + tj * 16 + quad * 4];

  f32x4 acc[4][4];
  #pragma unroll
  for (int ti = 0; ti < 4; ++ti)
    #pragma unroll
    for (int tj = 0; tj < 4; ++tj) acc[ti][tj] = qn[tj] + pn[ti];

  #pragma unroll
  for (int kstep = 0; kstep < 2; ++kstep) {
    const int kc = kstep * 4 + quad;
    s16x8 af[4], bf[4];
    #pragma unroll
    for (int ti = 0; ti < 4; ++ti)
      af[ti] = *(const s16x8*)(sm.A + swiz_off(wave_row + ti * 16 + m16, kc));
    #pragma unroll
    for (int tj = 0; tj < 4; ++tj)
      bf[tj] = *(const s16x8*)(sm.B + swiz_off(wave_col + tj * 16 + m16, kc));
    #pragma unroll
    for (int ti = 0; ti < 4; ++ti)
      #pragma unroll
      for (int tj = 0; tj < 4; ++tj)
        acc[ti][tj] = __builtin_amdgcn_mfma_f32_16x16x32_bf16(
            bf[tj], af[ti], acc[ti][tj], 0, 0, 0);   // swapped operands
  }

  // epilogue (r9-proven form): sq -> sqrt -> exp -> e5m2 pack -> dword store
  float rs[4] = {0.f, 0.f, 0.f, 0.f};
  #pragma unroll
  for (int ti = 0; ti < 4; ++ti) {
    unsigned char* rowp =
        K + (size_t)(bi + wave_row + ti * 16 + m16) * NROWS + bj + wave_col + quad * 4;
    #pragma unroll
    for (int tj = 0; tj < 4; ++tj) {
      f32x4 sq = acc[ti][tj];
      float k0 = __expf(-10.f * __builtin_amdgcn_sqrtf(fmaxf(sq.x, 0.f)));
      float k1 = __expf(-10.f * __builtin_amdgcn_sqrtf(fmaxf(sq.y, 0.f)));
      float k2 = __expf(-10.f * __builtin_amdgcn_sqrtf(fmaxf(sq.z, 0.f)));
      float k3 = __expf(-10.f * __builtin_amdgcn_sqrtf(fmaxf(sq.w, 0.f)));
      int pk = __builtin_amdgcn_cvt_pk_bf8_f32(k0, k1, 0, false);
      pk     = __builtin_amdgcn_cvt_pk_bf8_f32(k2, k3, pk, true);
      *(uint32_t*)(rowp + tj * 16) = (uint32_t)pk;
      rs[ti] += (k0 + k1) + (k2 + k3);
    }
  }
  #pragma unroll
  for (int ti = 0; ti < 4; ++ti) {
    float v = rs[ti];
    v += __shfl_xor(v, 16, 64);
    v += __shfl_xor(v, 32, 64);
    if (quad == 0) atomicAdd(&rowsum[bi + wave_row + ti * 16 + m16], v);
  }
}

// ---------- matvec4: 2048 blocks, 4 rows/block, 1 row/wave (max TLP) ----------

__global__ __launch_bounds__(256) void matvec4_kernel(
    const unsigned char* __restrict__ K, const float* __restrict__ x,
    float* __restrict__ y) {
  __shared__ uint32_t xsh[NROWS / 2];   // 16 KB packed f16 pairs
  const int t    = threadIdx.x;
  const int lane = t & 63;
  const int w    = t >> 6;

  const float4* x4 = (const float4*)x;
  #pragma unroll
  for (int i = 0; i < 8; ++i) {
    float4 xv = x4[t + i * 256];
    uint32_t lo = __builtin_bit_cast(uint32_t, __builtin_amdgcn_cvt_pkrtz(xv.x, xv.y));
    uint32_t hi = __builtin_bit_cast(uint32_t, __builtin_amdgcn_cvt_pkrtz(xv.z, xv.w));
    *(uint2*)&xsh[2 * t + 512 * i] = uint2{lo, hi};
  }
  __syncthreads();

  const int row = blockIdx.x * 4 + w;
  const uint4* k4 = (const uint4*)(K + (size_t)row * NROWS);
  float a0 = 0.f, a1 = 0.f, a2 = 0.f, a3 = 0.f;
  #pragma unroll
  for (int s = 0; s < 8; ++s) {
    uint4 kw = k4[s * 64 + lane];
    int base = (s * 64 + lane) * 8;
    uint4 xa = *(const uint4*)&xsh[base];
    uint4 xb = *(const uint4*)&xsh[base + 4];
    MV_DOT(kw.x, xa.x, xa.y, a0, a1)
    MV_DOT(kw.y, xa.z, xa.w, a2, a3)
    MV_DOT(kw.z, xb.x, xb.y, a0, a1)
    MV_DOT(kw.w, xb.z, xb.w, a2, a3)
  }
  float s = wave_reduce_add((a0 + a1) + (a2 + a3));
  if (lane == 0) y[row] = 1.0f / s;
}

// ---------- final4: fused 10th matvec + loss, 4 rows/block ----------

__global__ __launch_bounds__(256) void final4_kernel(
    const unsigned char* __restrict__ K, const float* __restrict__ v,
    float* __restrict__ partials) {
  __shared__ uint32_t xsh[NROWS / 2];
  __shared__ float sred[4];
  const int t    = threadIdx.x;
  const int lane = t & 63;
  const int w    = t >> 6;

  const float4* x4 = (const float4*)v;
  #pragma unroll
  for (int i = 0; i < 8; ++i) {
    float4 xv = x4[t + i * 256];
    uint32_t lo = __builtin_bit_cast(uint32_t, __builtin_amdgcn_cvt_pkrtz(xv.x, xv.y));
    uint32_t hi = __builtin_bit_cast(uint32_t, __builtin_amdgcn_cvt_pkrtz(xv.z, xv.w));
    *(uint2*)&xsh[2 * t + 512 * i] = uint2{lo, hi};
  }
  __syncthreads();

  const int row = blockIdx.x * 4 + w;
  const uint4* k4 = (const uint4*)(K + (size_t)row * NROWS);
  float s1 = 0.f, s2 = 0.f;
  #pragma unroll
  for (int s = 0; s < 8; ++s) {
    uint4 kw = k4[s * 64 + lane];
    int base = (s * 64 + lane) * 8;
    uint4 xa = *(const uint4*)&xsh[base];
    uint4 xb = *(const uint4*)&xsh[base + 4];
    FN_DOT(kw.x, xa.x, xa.y, s1, s2)
    FN_DOT(kw.y, xa.z, xa.w, s1, s2)
    FN_DOT(kw.z, xb.x, xb.y, s1, s2)
    FN_DOT(kw.w, xb.z, xb.w, s1, s2)
  }
  s1 = wave_reduce_add(s1);
  s2 = wave_reduce_add(s2);
  if (lane == 0) sred[w] = (-EPS) * s2 / s1;
  __syncthreads();
  if (t == 0) partials[blockIdx.x] = sred[0] + sred[1] + sred[2] + sred[3];
}

// Sum 2048 partials -> out[0].
__global__ __launch_bounds__(256) void reduce_kernel(
    const float* __restrict__ partials, float* __restrict__ out) {
  const int t = threadIdx.x;
  float s = 0.f;
  #pragma unroll
  for (int i = 0; i < 8; ++i) s += partials[t + i * 256];
  s = wave_reduce_add(s);
  __shared__ float red[4];
  int lane = t & 63, wid = t >> 6;
  if (lane == 0) red[wid] = s;
  __syncthreads();
  if (t == 0) out[0] = red[0] + red[1] + red[2] + red[3];
}

// ---------- launch ----------

extern "C" void kernel_launch(void* const* d_in, const int* in_sizes, int n_in,
                              void* d_out, int out_size, void* d_ws, size_t ws_size,
                              hipStream_t stream) {
  const float* P = (const float*)d_in[0];
  const float* Q = (const float*)d_in[1];
  float* out = (float*)d_out;

  char* ws = (char*)d_ws;
  unsigned char* K = (unsigned char*)ws;                 // 8192*8192 = 67108864 B
  float* p2 = (float*)(ws + (size_t)NROWS * NROWS);
  float* q2 = p2 + NROWS;
  float* ub = q2 + NROWS;
  float* vb = ub + NROWS;
  float* partials = vb + NROWS;                          // 2048 floats (pad to 8192)
  float* rowsum   = partials + NROWS;                    // 8192 floats

  rownorm_kernel<<<(2 * NROWS) / 4, 256, 0, stream>>>(P, Q, p2, q2, rowsum);
  kgen_kernel<<<dim3(NROWS / 128, NROWS / 128), 256, 0, stream>>>(P, Q, p2, q2, K, rowsum);
  v1_kernel<<<NROWS / 256, 256, 0, stream>>>(rowsum, vb);

  // Passes m=1..8 (m=0 fused into kgen rowsum): after m=8, vb holds v5.
  for (int m = 1; m < 9; ++m) {
    const float* xin = (m & 1) ? vb : ub;
    float* yout      = (m & 1) ? ub : vb;
    matvec4_kernel<<<NROWS / 4, 256, 0, stream>>>(K, xin, yout);
  }

  final4_kernel<<<NROWS / 4, 256, 0, stream>>>(K, vb, partials);
  reduce_kernel<<<1, 256, 0, stream>>>(partials, out);
}

// Round 12
// 243.288 us; speedup vs baseline: 5.7843x; 1.0355x over previous
//
#include <hip/hip_runtime.h>
#include <hip/hip_fp16.h>
#include <stdint.h>

#define NROWS 8192
#define DIM 64
#define EPS 0.1f

typedef float f32x4 __attribute__((ext_vector_type(4)));
typedef short s16x8 __attribute__((ext_vector_type(8)));
typedef _Float16 h2 __attribute__((ext_vector_type(2)));

// ---------- helpers ----------

__device__ __forceinline__ float wave_reduce_add(float v) {
  #pragma unroll
  for (int off = 32; off > 0; off >>= 1) v += __shfl_down(v, off, 64);
  return v;
}

// pack two fp32 -> bf16x2 dword by truncation (1 v_perm); x -> low, y -> high.
__device__ __forceinline__ uint32_t pack_bf16_trunc(float x, float y) {
  return __builtin_amdgcn_perm(__float_as_uint(y), __float_as_uint(x), 0x07060302u);
}

// ---------- fp4 e2m1 encode/decode (block-scaled, scale applied manually) ----

// decode: byte `sel` of kd (2 nibbles) -> packed f16 pair {lo, hi}
#if __has_builtin(__builtin_amdgcn_cvt_scalef32_pk_f16_fp4)
#define CVT4H(kd, sel) __builtin_amdgcn_cvt_scalef32_pk_f16_fp4((kd), 1.0f, (sel))
#else
__device__ __forceinline__ h2 cvt4h_fb(uint32_t kd, int sel) {
  uint32_t byt  = (kd >> (sel * 8)) & 0xFFu;
  uint32_t selv = (byt & 0xFu) | ((byt >> 4) << 16);
  // f16 high bytes of values {0,0.5,1,1.5 | 2,3,4,6}
  uint32_t tb = __builtin_amdgcn_perm(0x46444240u, 0x3E3C3800u, selv);
  uint32_t d  = ((tb & 0xFFu) << 8) | ((tb & 0xFF0000u) << 8);
  return __builtin_bit_cast(h2, d);
}
#define CVT4H(kd, sel) cvt4h_fb((kd), (sel))
#endif

// encode: 4 pre-scaled floats in [0,4] -> 4 e2m1 nibbles (low 16 bits)
#if __has_builtin(__builtin_amdgcn_cvt_scalef32_pk_fp4_f32)
__device__ __forceinline__ uint32_t enc4(float q0, float q1, float q2, float q3) {
  uint32_t pk = __builtin_amdgcn_cvt_scalef32_pk_fp4_f32(0u, q0, q1, 1.0f, 0);
  pk = __builtin_amdgcn_cvt_scalef32_pk_fp4_f32(pk, q2, q3, 1.0f, 1);
  return pk & 0xFFFFu;
}
#else
__device__ __forceinline__ uint32_t enc1(float q) {
  float c = fminf(floorf(2.f * q + 0.5f), 4.f);
  c += (q > 2.5f) ? 1.f : 0.f;
  c += (q > 3.5f) ? 1.f : 0.f;
  return (uint32_t)c;
}
__device__ __forceinline__ uint32_t enc4(float q0, float q1, float q2, float q3) {
  return enc1(q0) | (enc1(q1) << 4) | (enc1(q2) << 8) | (enc1(q3) << 12);
}
#endif

#define FP4DOT(kd, xv, acc)                                                          \
  acc = __builtin_amdgcn_fdot2(CVT4H((kd), 0), __builtin_bit_cast(h2, (xv).x), acc, false); \
  acc = __builtin_amdgcn_fdot2(CVT4H((kd), 1), __builtin_bit_cast(h2, (xv).y), acc, false); \
  acc = __builtin_amdgcn_fdot2(CVT4H((kd), 2), __builtin_bit_cast(h2, (xv).z), acc, false); \
  acc = __builtin_amdgcn_fdot2(CVT4H((kd), 3), __builtin_bit_cast(h2, (xv).w), acc, false);

#define FIN1(kd, xd_, sel)                                                           \
  {                                                                                  \
    h2 kvp = CVT4H((kd), sel);                                                       \
    h2 xp  = __builtin_bit_cast(h2, (xd_));                                          \
    s1b = __builtin_amdgcn_fdot2(kvp, xp, s1b, false);                               \
    float v0 = (float)kvp.x, v1 = (float)kvp.y;                                      \
    float x0 = (float)xp.x,  x1 = (float)xp.y;                                       \
    t2b = fmaf(v0 * x0, __logf(fmaxf(v0, 1e-8f)), t2b);                              \
    t2b = fmaf(v1 * x1, __logf(fmaxf(v1, 1e-8f)), t2b);                              \
  }
#define FINDOT(kd, xv) FIN1(kd, (xv).x, 0) FIN1(kd, (xv).y, 1) FIN1(kd, (xv).z, 2) FIN1(kd, (xv).w, 3)

// ---------- small kernels ----------

__global__ __launch_bounds__(256) void rownorm_kernel(
    const float* __restrict__ P, const float* __restrict__ Q,
    float* __restrict__ p2, float* __restrict__ q2,
    float* __restrict__ rowsum) {
  int wid  = threadIdx.x >> 6;
  int lane = threadIdx.x & 63;
  int row  = blockIdx.x * 4 + wid;  // 0..16383
  const float* X;
  float* out;
  int r;
  if (row < NROWS) { X = P; out = p2; r = row; }
  else             { X = Q; out = q2; r = row - NROWS; }
  float v = X[(size_t)r * DIM + lane];
  float s = wave_reduce_add(v * v);
  if (lane == 0) out[r] = s;
  if (row < NROWS && lane == 1) rowsum[r] = 0.f;   // zero for kgen's atomics
}

// vb16[i] = f16(64 / rowsum[i])  (pass m=0 fused into kgen's rowsum)
__global__ void v1_kernel(const float* __restrict__ rowsum,
                          unsigned short* __restrict__ vb16) {
  int i = blockIdx.x * blockDim.x + threadIdx.x;
  if (i < NROWS) vb16[i] = __half_as_ushort(__float2half(64.0f / rowsum[i]));
}

// ---------- kgen: MFMA bf16 -> fp4 K (nibbles) + e8m0 scales + row sums ----

struct KgenSmem {
  unsigned char A[128 * 128];   // -2P tile, bf16, swizzled
  unsigned char B[128 * 128];   // Q tile, bf16, swizzled
  float p2s[128];
  float q2s[128];
};

__device__ __forceinline__ int swiz_off(int row, int kc) {
  return row * 128 + ((kc ^ (row & 7)) << 4);
}

__global__ __launch_bounds__(256) void kgen_kernel(
    const float* __restrict__ P, const float* __restrict__ Q,
    const float* __restrict__ p2, const float* __restrict__ q2,
    unsigned char* __restrict__ K4, unsigned char* __restrict__ scales,
    float* __restrict__ rowsum) {
  __shared__ KgenSmem sm;
  const int t  = threadIdx.x;
  const int bi = blockIdx.y * 128;
  const int bj = blockIdx.x * 128;

  {
    const float4* P4 = (const float4*)(P + (size_t)bi * DIM);
    const float4* Q4 = (const float4*)(Q + (size_t)bj * DIM);
    #pragma unroll
    for (int it = 0; it < 4; ++it) {
      int idx = t + it * 256;
      int row = idx >> 3;
      int kc  = idx & 7;
      int g   = row * 16 + kc * 2;
      float4 a0 = P4[g], a1 = P4[g + 1];
      float4 b0 = Q4[g], b1 = Q4[g + 1];
      uint4 pa, pb;
      pa.x = pack_bf16_trunc(-2.f * a0.x, -2.f * a0.y);
      pa.y = pack_bf16_trunc(-2.f * a0.z, -2.f * a0.w);
      pa.z = pack_bf16_trunc(-2.f * a1.x, -2.f * a1.y);
      pa.w = pack_bf16_trunc(-2.f * a1.z, -2.f * a1.w);
      pb.x = pack_bf16_trunc(b0.x, b0.y);
      pb.y = pack_bf16_trunc(b0.z, b0.w);
      pb.z = pack_bf16_trunc(b1.x, b1.y);
      pb.w = pack_bf16_trunc(b1.z, b1.w);
      *(uint4*)(sm.A + swiz_off(row, kc)) = pa;
      *(uint4*)(sm.B + swiz_off(row, kc)) = pb;
    }
    if (t < 128)                   sm.p2s[t]       = p2[bi + t];
    else                           sm.q2s[t - 128] = q2[bj + t - 128];
  }
  __syncthreads();

  const int w        = t >> 6;
  const int lane     = t & 63;
  const int quad     = lane >> 4;
  const int m16      = lane & 15;
  const int wave_row = (w >> 1) * 64;
  const int wave_col = (w & 1) * 64;

  float pn[4];
  f32x4 qn[4];
  #pragma unroll
  for (int ti = 0; ti < 4; ++ti) pn[ti] = sm.p2s[wave_row + ti * 16 + m16];
  #pragma unroll
  for (int tj = 0; tj < 4; ++tj)
    qn[tj] = *(const f32x4*)&sm.q2s[wave_col + tj * 16 + quad * 4];

  f32x4 acc[4][4];
  #pragma unroll
  for (int ti = 0; ti < 4; ++ti)
    #pragma unroll
    for (int tj = 0; tj < 4; ++tj) acc[ti][tj] = qn[tj] + pn[ti];

  #pragma unroll
  for (int kstep = 0; kstep < 2; ++kstep) {
    const int kc = kstep * 4 + quad;
    s16x8 af[4], bf[4];
    #pragma unroll
    for (int ti = 0; ti < 4; ++ti)
      af[ti] = *(const s16x8*)(sm.A + swiz_off(wave_row + ti * 16 + m16, kc));
    #pragma unroll
    for (int tj = 0; tj < 4; ++tj)
      bf[tj] = *(const s16x8*)(sm.B + swiz_off(wave_col + tj * 16 + m16, kc));
    #pragma unroll
    for (int ti = 0; ti < 4; ++ti)
      #pragma unroll
      for (int tj = 0; tj < 4; ++tj)
        acc[ti][tj] = __builtin_amdgcn_mfma_f32_16x16x32_bf16(
            bf[tj], af[ti], acc[ti][tj], 0, 0, 0);   // swapped operands
  }

  // epilogue: k = exp(-10*sqrt(sq)); per-32col block max -> e8m0 scale;
  // quantize to e2m1 nibbles; ushort stores; fused rowsum.
  #pragma unroll
  for (int ti = 0; ti < 4; ++ti) {
    const int row = bi + wave_row + ti * 16 + m16;
    float kv[4][4];
    float mlo = 0.f, mhi = 0.f, rs = 0.f;
    #pragma unroll
    for (int tj = 0; tj < 4; ++tj) {
      f32x4 sq = acc[ti][tj];
      kv[tj][0] = __expf(-10.f * __builtin_amdgcn_sqrtf(fmaxf(sq.x, 0.f)));
      kv[tj][1] = __expf(-10.f * __builtin_amdgcn_sqrtf(fmaxf(sq.y, 0.f)));
      kv[tj][2] = __expf(-10.f * __builtin_amdgcn_sqrtf(fmaxf(sq.z, 0.f)));
      kv[tj][3] = __expf(-10.f * __builtin_amdgcn_sqrtf(fmaxf(sq.w, 0.f)));
      float mt = fmaxf(fmaxf(kv[tj][0], kv[tj][1]), fmaxf(kv[tj][2], kv[tj][3]));
      if (tj < 2) mlo = fmaxf(mlo, mt); else mhi = fmaxf(mhi, mt);
      rs += (kv[tj][0] + kv[tj][1]) + (kv[tj][2] + kv[tj][3]);
    }
    mlo = fmaxf(mlo, __shfl_xor(mlo, 16, 64));
    mlo = fmaxf(mlo, __shfl_xor(mlo, 32, 64));
    mhi = fmaxf(mhi, __shfl_xor(mhi, 16, 64));
    mhi = fmaxf(mhi, __shfl_xor(mhi, 32, 64));
    // S = 2^(e-1) where e = floor(log2(max)); max/S in [2,4)
    uint32_t eblo = (__float_as_uint(mlo) >> 23) - 1u;
    uint32_t ebhi = (__float_as_uint(mhi) >> 23) - 1u;
    float silo = __uint_as_float((254u - eblo) << 23);   // 1/S
    float sihi = __uint_as_float((254u - ebhi) << 23);
    #pragma unroll
    for (int tj = 0; tj < 4; ++tj) {
      float si = (tj < 2) ? silo : sihi;
      uint32_t pk = enc4(kv[tj][0] * si, kv[tj][1] * si,
                         kv[tj][2] * si, kv[tj][3] * si);
      *(unsigned short*)(K4 + (size_t)row * (NROWS / 2) +
                         ((bj + wave_col + tj * 16 + quad * 4) >> 1)) =
          (unsigned short)pk;
    }
    if (quad == 0) {
      *(unsigned short*)(scales + (size_t)row * 256 + ((bj + wave_col) >> 5)) =
          (unsigned short)((eblo & 0xFFu) | ((ebhi & 0xFFu) << 8));
    }
    float v = rs;
    v += __shfl_xor(v, 16, 64);
    v += __shfl_xor(v, 32, 64);
    if (quad == 0) atomicAdd(&rowsum[row], v);
  }
}

// ---------- matvec_fp4: 2048 blocks, 1 row/wave, no LDS (x f16 from L1) ----

__global__ __launch_bounds__(256) void matvec_fp4(
    const unsigned char* __restrict__ K4, const unsigned char* __restrict__ scales,
    const unsigned short* __restrict__ xin, unsigned short* __restrict__ yout) {
  const int t = threadIdx.x, lane = t & 63, w = t >> 6;
  const int row = blockIdx.x * 4 + w;
  const uint4* krow = (const uint4*)(K4 + (size_t)row * (NROWS / 2));
  const unsigned char* srow = scales + (size_t)row * 256;
  const uint4* x4 = (const uint4*)xin;   // 8192 f16 = 1024 uint4
  float total = 0.f;
  #pragma unroll
  for (int s = 0; s < 4; ++s) {
    const int b = s * 64 + lane;           // 32-elem block index
    uint4 kq = krow[b];
    float S = __uint_as_float((uint32_t)srow[b] << 23);
    uint4 xa = x4[b * 4 + 0], xb = x4[b * 4 + 1];
    uint4 xc = x4[b * 4 + 2], xd = x4[b * 4 + 3];
    float a0 = 0.f, a1 = 0.f;
    FP4DOT(kq.x, xa, a0)
    FP4DOT(kq.y, xb, a1)
    FP4DOT(kq.z, xc, a0)
    FP4DOT(kq.w, xd, a1)
    total = fmaf(S, a0 + a1, total);
  }
  float sm = wave_reduce_add(total);
  if (lane == 0) yout[row] = __half_as_ushort(__float2half(1.0f / sm));
}

// ---------- final_fp4: fused 10th matvec + loss ----------
// K = S*v; s1 = sum K x; s2 = sum K x lnK = S*(lnS*s1b + sum v x ln v)

__global__ __launch_bounds__(256) void final_fp4(
    const unsigned char* __restrict__ K4, const unsigned char* __restrict__ scales,
    const unsigned short* __restrict__ xin, float* __restrict__ partials) {
  const int t = threadIdx.x, lane = t & 63, w = t >> 6;
  const int row = blockIdx.x * 4 + w;
  const uint4* krow = (const uint4*)(K4 + (size_t)row * (NROWS / 2));
  const unsigned char* srow = scales + (size_t)row * 256;
  const uint4* x4 = (const uint4*)xin;
  float s1 = 0.f, s2 = 0.f;
  #pragma unroll
  for (int s = 0; s < 4; ++s) {
    const int b = s * 64 + lane;
    uint4 kq = krow[b];
    uint32_t sb = srow[b];
    float S = __uint_as_float(sb << 23);
    float lnS = ((float)(int)sb - 127.f) * 0.69314718f;
    uint4 xa = x4[b * 4 + 0], xb = x4[b * 4 + 1];
    uint4 xc = x4[b * 4 + 2], xd = x4[b * 4 + 3];
    float s1b = 0.f, t2b = 0.f;
    FINDOT(kq.x, xa)
    FINDOT(kq.y, xb)
    FINDOT(kq.z, xc)
    FINDOT(kq.w, xd)
    s1 = fmaf(S, s1b, s1);
    s2 = fmaf(S, fmaf(lnS, s1b, t2b), s2);
  }
  s1 = wave_reduce_add(s1);
  s2 = wave_reduce_add(s2);
  __shared__ float sred[4];
  if (lane == 0) sred[w] = (-EPS) * s2 / s1;
  __syncthreads();
  if (t == 0) partials[blockIdx.x] = sred[0] + sred[1] + sred[2] + sred[3];
}

// Sum 2048 partials -> out[0].
__global__ __launch_bounds__(256) void reduce_kernel(
    const float* __restrict__ partials, float* __restrict__ out) {
  const int t = threadIdx.x;
  float s = 0.f;
  #pragma unroll
  for (int i = 0; i < 8; ++i) s += partials[t + i * 256];
  s = wave_reduce_add(s);
  __shared__ float red[4];
  int lane = t & 63, wid = t >> 6;
  if (lane == 0) red[wid] = s;
  __syncthreads();
  if (t == 0) out[0] = red[0] + red[1] + red[2] + red[3];
}

// ---------- launch ----------

extern "C" void kernel_launch(void* const* d_in, const int* in_sizes, int n_in,
                              void* d_out, int out_size, void* d_ws, size_t ws_size,
                              hipStream_t stream) {
  const float* P = (const float*)d_in[0];
  const float* Q = (const float*)d_in[1];
  float* out = (float*)d_out;

  char* ws = (char*)d_ws;
  unsigned char* K4     = (unsigned char*)ws;                    // 33554432 B
  unsigned char* scales = (unsigned char*)(ws + 33554432);       // 2097152 B
  float* p2       = (float*)(ws + 35651584);
  float* q2       = p2 + NROWS;
  float* rowsum   = q2 + NROWS;
  float* partials = rowsum + NROWS;                              // 2048 (slot 8192)
  unsigned short* ub16 = (unsigned short*)(partials + NROWS);
  unsigned short* vb16 = ub16 + NROWS;

  rownorm_kernel<<<(2 * NROWS) / 4, 256, 0, stream>>>(P, Q, p2, q2, rowsum);
  kgen_kernel<<<dim3(NROWS / 128, NROWS / 128), 256, 0, stream>>>(
      P, Q, p2, q2, K4, scales, rowsum);
  v1_kernel<<<NROWS / 256, 256, 0, stream>>>(rowsum, vb16);

  // Passes m=1..8 (m=0 fused into kgen rowsum): after m=8, vb16 holds v5.
  for (int m = 1; m < 9; ++m) {
    const unsigned short* xin = (m & 1) ? vb16 : ub16;
    unsigned short* yout      = (m & 1) ? ub16 : vb16;
    matvec_fp4<<<NROWS / 4, 256, 0, stream>>>(K4, scales, xin, yout);
  }

  final_fp4<<<NROWS / 4, 256, 0, stream>>>(K4, scales, vb16, partials);
  reduce_kernel<<<1, 256, 0, stream>>>(partials, out);
}